// Round 5
// baseline (23.728 us; speedup 1.0000x reference)
//
#include <hip/hip_runtime.h>

namespace {
constexpr float kEps = 1e-6f;
constexpr int kNPix = 90000;        // 300*300
constexpr int kImgStride = 270000;  // 3*kNPix
constexpr int kQuads = 360000;      // total float4 pixel-groups (1.44M px / 4)
constexpr int kQuadsPerImg = 22500;
constexpr int kPal = 30;
constexpr int kBlock = 384;         // 6 waves
constexpr int kGrid = 256;          // 1 block per CU
constexpr double kInvSize = 1.0 / 4320000.0;  // 16*3*300*300
}  // namespace

// Single fused kernel. Per block: partial sum of min-palette color distance
// over 16 px/thread (amortizes the 30 broadcast ds_read_b128 of the palette
// loop over 16 pixels -> LDS ~0.8us/CU, under the ~1.9us VALU floor).
// Cross-block: last-block-done reduction (counter + device fences), final
// sum in fixed-order double -> deterministic output.
// dist^2 + eps = (x^2+y^2+z^2) + min_p( -2a'x -2b'y -2c'z + (|a'|^2 + eps) ),
// a' = a - eps (folds the reference's "+EPS on diff").
__global__ __launch_bounds__(384) void nps_main_kernel(
    const float* __restrict__ patch, const float* __restrict__ pal,
    float* __restrict__ partial, unsigned int* __restrict__ counter,
    float* __restrict__ out) {
  __shared__ float4 lpal[kPal];
  if (threadIdx.x < kPal) {
    const int p = threadIdx.x;
    const float a = pal[(p * 3 + 0) * kNPix] - kEps;
    const float b = pal[(p * 3 + 1) * kNPix] - kEps;
    const float c = pal[(p * 3 + 2) * kNPix] - kEps;
    lpal[p] = make_float4(-2.f * a, -2.f * b, -2.f * c,
                          fmaf(a, a, fmaf(b, b, fmaf(c, c, kEps))));
  }
  __syncthreads();

  // 4 interleaved float4 groups per thread: lane-consecutive addresses.
  float x[16], y[16], z[16], msk[4];
  const int t = threadIdx.x;
#pragma unroll
  for (int g = 0; g < 4; ++g) {
    const int f = blockIdx.x * (kBlock * 4) + g * kBlock + t;
    const bool act = (f < kQuads);
    msk[g] = act ? 1.f : 0.f;
    const int fi = act ? f : 0;
    const int img = fi / kQuadsPerImg;
    const int r = fi - img * kQuadsPerImg;
    const float* base = patch + (size_t)img * kImgStride + r * 4;
    const float4 vx = *reinterpret_cast<const float4*>(base);
    const float4 vy = *reinterpret_cast<const float4*>(base + kNPix);
    const float4 vz = *reinterpret_cast<const float4*>(base + 2 * kNPix);
    x[4 * g + 0] = vx.x; x[4 * g + 1] = vx.y; x[4 * g + 2] = vx.z; x[4 * g + 3] = vx.w;
    y[4 * g + 0] = vy.x; y[4 * g + 1] = vy.y; y[4 * g + 2] = vy.z; y[4 * g + 3] = vy.w;
    z[4 * g + 0] = vz.x; z[4 * g + 1] = vz.y; z[4 * g + 2] = vz.z; z[4 * g + 3] = vz.w;
  }

  float md[16];
#pragma unroll
  for (int j = 0; j < 16; ++j) md[j] = 3.4e38f;
  // Palette in pairs: fminf(fminf(md,d0),d1) fuses to v_min3_f32.
#pragma unroll 3
  for (int p = 0; p < kPal; p += 2) {
    const float4 c0 = lpal[p];
    const float4 c1 = lpal[p + 1];
#pragma unroll
    for (int j = 0; j < 16; ++j) {
      const float d0 =
          fmaf(x[j], c0.x, fmaf(y[j], c0.y, fmaf(z[j], c0.z, c0.w)));
      const float d1 =
          fmaf(x[j], c1.x, fmaf(y[j], c1.y, fmaf(z[j], c1.z, c1.w)));
      md[j] = fminf(fminf(md[j], d0), d1);
    }
  }

  float acc = 0.f;
#pragma unroll
  for (int g = 0; g < 4; ++g) {
#pragma unroll
    for (int jj = 0; jj < 4; ++jj) {
      const int j = 4 * g + jj;
      const float s = fmaf(x[j], x[j], fmaf(y[j], y[j], z[j] * z[j])) + md[j];
      acc += msk[g] * sqrtf(s);
    }
  }

  // Block reduction: wave shuffle, then LDS across the 6 waves.
#pragma unroll
  for (int off = 32; off > 0; off >>= 1) acc += __shfl_down(acc, off, 64);
  __shared__ float warp_sums[6];
  const int lane = threadIdx.x & 63;
  const int wid = threadIdx.x >> 6;
  if (lane == 0) warp_sums[wid] = acc;
  __syncthreads();

  __shared__ bool is_last;
  if (threadIdx.x == 0) {
    float s = warp_sums[0];
#pragma unroll
    for (int w = 1; w < 6; ++w) s += warp_sums[w];
    partial[blockIdx.x] = s;
    __threadfence();  // make partial visible device-wide before counting
    const unsigned int old = atomicAdd(counter, 1u);
    is_last = (old == (unsigned int)(kGrid - 1));
  }
  __syncthreads();

  // Last block: deterministic fixed-order double reduction of 256 partials.
  if (is_last) {
    __threadfence();  // acquire: see all partials
    if (wid == 0) {
      double d = 0.0;
#pragma unroll
      for (int k = 0; k < kGrid / 64; ++k)
        d += (double)partial[k * 64 + lane];
#pragma unroll
      for (int off = 32; off > 0; off >>= 1) d += __shfl_down(d, off, 64);
      if (lane == 0) out[0] = (float)(d * kInvSize);
    }
  }
}

extern "C" void kernel_launch(void* const* d_in, const int* in_sizes, int n_in,
                              void* d_out, int out_size, void* d_ws,
                              size_t ws_size, hipStream_t stream) {
  const float* patch = (const float*)d_in[0];  // [16,3,300,300] f32
  const float* pal = (const float*)d_in[1];    // [30,3,300,300] f32 (bcast colors)
  float* out = (float*)d_out;                  // scalar f32
  unsigned int* counter = (unsigned int*)d_ws; // 4B counter at ws[0]
  float* partial = (float*)d_ws + 16;          // 256 partials after it

  hipMemsetAsync(d_ws, 0, 4, stream);          // re-zero counter each replay
  nps_main_kernel<<<kGrid, kBlock, 0, stream>>>(patch, pal, partial, counter,
                                                out);
}